// Round 10
// baseline (161.704 us; speedup 1.0000x reference)
//
#include <hip/hip_runtime.h>

// GSHashEncoding R10: producer/consumer wave specialization (no barriers).
//   waves 3-4 (128 lanes): pure gather -> 4-slot LDS ring (depth-2 pipelined,
//     unconditional loads -> clean per-wave vmcnt, no stores in their queue)
//   waves 0-2 (192 lanes): pure consume -> matvec (W in VGPRs) -> coalesced
//     nontemporal float4 stores (never touch an MSHR)
//   sync: monotone LDS counters pcnt/ccnt + s_sleep spin.
// k1: codes fp32 -> bf16 table in ws (2.62 MB, L2-resident).
// TPB=16 -> NBLK=512 = 2 blocks/CU all-resident; 10 waves/CU.

#define RESO    2097152
#define OUT_DIM 48
#define LVL0    65536
#define NCODES  327680
#define BLK     320                    // 5 waves: 3 consumer + 2 producer
#define NCONS   192                    // t <  192: consumers (192 % 12 == 0)
#define TILE    256
#define NITER   16                     // TILE / (NCONS/12)
#define TPB     16                     // tiles per block
#define NSLOT   4                      // LDS ring slots
#define NBLK    (RESO / (TILE * TPB))  // 512

typedef int            vi4 __attribute__((ext_vector_type(4)));
typedef float          vf4 __attribute__((ext_vector_type(4)));
typedef unsigned short vu4 __attribute__((ext_vector_type(4)));

static __device__ __forceinline__ unsigned short f2bf_rne(float x) {
    unsigned int u = __float_as_uint(x);
    u += 0x7fffu + ((u >> 16) & 1u);
    return (unsigned short)(u >> 16);
}
static __device__ __forceinline__ float bf2f(unsigned short h) {
    return __uint_as_float(((unsigned int)h) << 16);
}

// ---- k1: codes fp32 -> bf16 table ----
__global__ __launch_bounds__(256) void convert_kernel(
    const float* __restrict__ codes, unsigned short* __restrict__ bf)
{
    const int i = blockIdx.x * 256 + threadIdx.x;
    const vf4 v = ((const vf4*)codes)[i];
    vu4 o;
    o.x = f2bf_rne(v.x); o.y = f2bf_rne(v.y);
    o.z = f2bf_rne(v.z); o.w = f2bf_rne(v.w);
    ((vu4*)bf)[i] = o;
}

// ---- k2: producer/consumer kernel ----
__global__ __launch_bounds__(BLK) void gshash_pc_kernel(
    const unsigned short* __restrict__ tab,
    const float* __restrict__ W,
    const vi4*   __restrict__ map0,
    const vi4*   __restrict__ map1,
    float*       __restrict__ out)
{
    __shared__ float feats[NSLOT][TILE * 8];   // 32 KB ring
    __shared__ int   pcnt[NSLOT];              // producer-wave completions (2/pass)
    __shared__ int   ccnt[NSLOT];              // consumer-wave completions (3/pass)

    const int t = threadIdx.x;
    if (t < NSLOT) { pcnt[t] = 0; ccnt[t] = 0; }
    __syncthreads();                            // only barrier in the kernel

    const size_t row00 = (size_t)blockIdx.x * (TPB * TILE);
    volatile int* vp = pcnt;
    volatile int* vc = ccnt;

    if (t >= NCONS) {
        // ===================== producers (waves 3,4) =====================
        const int p = t - NCONS;                // 0..127; owns rows p, p+128
        const unsigned short* __restrict__ t1 = tab + LVL0 * 4;
        const bool lane0 = ((t & 63) == 0);

        vi4 MA0, MA1, NA0, NA1, MB0, MB1, NB0, NB1;
        unsigned short gA[16], gB[16];

        #define PMAPS(j, M0, M1, N0, N1) {                                   \
            const size_t r0 = row00 + (size_t)(j) * TILE;                    \
            M0 = __builtin_nontemporal_load(&map0[r0 + p]);                  \
            M1 = __builtin_nontemporal_load(&map1[r0 + p]);                  \
            N0 = __builtin_nontemporal_load(&map0[r0 + 128 + p]);            \
            N1 = __builtin_nontemporal_load(&map1[r0 + 128 + p]);            \
        }
        #define PGATH(M0, M1, N0, N1, G) {                                   \
            G[0]  = tab[M0.x * 4 + 0];  G[1]  = tab[M0.y * 4 + 1];           \
            G[2]  = tab[M0.z * 4 + 2];  G[3]  = tab[M0.w * 4 + 3];           \
            G[4]  = t1[M1.x * 4 + 0];   G[5]  = t1[M1.y * 4 + 1];            \
            G[6]  = t1[M1.z * 4 + 2];   G[7]  = t1[M1.w * 4 + 3];            \
            G[8]  = tab[N0.x * 4 + 0];  G[9]  = tab[N0.y * 4 + 1];           \
            G[10] = tab[N0.z * 4 + 2];  G[11] = tab[N0.w * 4 + 3];           \
            G[12] = t1[N1.x * 4 + 0];   G[13] = t1[N1.y * 4 + 1];            \
            G[14] = t1[N1.z * 4 + 2];   G[15] = t1[N1.w * 4 + 3];            \
        }
        #define PWRITE(G, s) {                                               \
            vf4 a, b, c, d;                                                  \
            a.x = bf2f(G[0]);  a.y = bf2f(G[1]);  a.z = bf2f(G[2]);  a.w = bf2f(G[3]);  \
            b.x = bf2f(G[4]);  b.y = bf2f(G[5]);  b.z = bf2f(G[6]);  b.w = bf2f(G[7]);  \
            c.x = bf2f(G[8]);  c.y = bf2f(G[9]);  c.z = bf2f(G[10]); c.w = bf2f(G[11]); \
            d.x = bf2f(G[12]); d.y = bf2f(G[13]); d.z = bf2f(G[14]); d.w = bf2f(G[15]); \
            *(vf4*)&feats[s][p * 8]             = a;                         \
            *(vf4*)&feats[s][p * 8 + 4]         = b;                         \
            *(vf4*)&feats[s][(128 + p) * 8]     = c;                         \
            *(vf4*)&feats[s][(128 + p) * 8 + 4] = d;                         \
        }

        // prolog: tile0 gathers in flight (gA), tile1 maps in flight (MB*)
        PMAPS(0, MA0, MA1, NA0, NA1);
        PGATH(MA0, MA1, NA0, NA1, gA);
        PMAPS(1, MB0, MB1, NB0, NB1);

        #pragma unroll
        for (int i = 0; i < TPB; ++i) {
            const int s = i & (NSLOT - 1);
            const int k = i >> 2;
            if ((i & 1) == 0) {
                if (i + 1 < TPB) PGATH(MB0, MB1, NB0, NB1, gB);   // tile i+1
                if (i + 2 < TPB) PMAPS(i + 2, MA0, MA1, NA0, NA1);
                while (vc[s] < 3 * k) __builtin_amdgcn_s_sleep(1); // slot free?
                asm volatile("" ::: "memory");
                PWRITE(gA, s);                                     // waits vmcnt for gA only
            } else {
                if (i + 1 < TPB) PGATH(MA0, MA1, NA0, NA1, gA);
                if (i + 2 < TPB) PMAPS(i + 2, MB0, MB1, NB0, NB1);
                while (vc[s] < 3 * k) __builtin_amdgcn_s_sleep(1);
                asm volatile("" ::: "memory");
                PWRITE(gB, s);
            }
            asm volatile("s_waitcnt lgkmcnt(0)" ::: "memory");     // ds_writes done
            if (lane0) atomicAdd(&pcnt[s], 1);
        }
        #undef PMAPS
        #undef PGATH
        #undef PWRITE
    } else {
        // ===================== consumers (waves 0-2) =====================
        const int col4  = t % 12;
        const int rbase = t / 12;                // 0..15
        vf4 Wv[8];
        #pragma unroll
        for (int w = 0; w < 8; ++w)
            Wv[w] = ((const vf4*)(W + w * OUT_DIM))[col4];

        for (int i = 0; i < TPB; ++i) {
            const int s = i & (NSLOT - 1);
            const int k = i >> 2;
            while (vp[s] < 2 * (k + 1)) __builtin_amdgcn_s_sleep(1); // tile ready?
            asm volatile("" ::: "memory");

            vf4* __restrict__ out4 = (vf4*)(out + (row00 + (size_t)i * TILE) * OUT_DIM);
            #pragma unroll
            for (int j = 0; j < NITER; ++j) {
                const int r = j * 16 + rbase;
                const vf4 fa = *(const vf4*)&feats[s][r * 8];
                const vf4 fb = *(const vf4*)&feats[s][r * 8 + 4];
                vf4 acc = fa.x * Wv[0];
                acc += fa.y * Wv[1];
                acc += fa.z * Wv[2];
                acc += fa.w * Wv[3];
                acc += fb.x * Wv[4];
                acc += fb.y * Wv[5];
                acc += fb.z * Wv[6];
                acc += fb.w * Wv[7];
                __builtin_nontemporal_store(acc, &out4[j * NCONS + t]);
            }
            asm volatile("s_waitcnt lgkmcnt(0)" ::: "memory");     // ds_reads done
            if ((t & 63) == 0) atomicAdd(&ccnt[s], 1);
        }
    }
}

// ---- fallback: fused fp32 single-tile kernel (if ws too small) ----
__global__ __launch_bounds__(192) void gshash_f32_kernel(
    const float* __restrict__ codes,
    const float* __restrict__ W,
    const vi4*   __restrict__ map0,
    const vi4*   __restrict__ map1,
    float*       __restrict__ out)
{
    __shared__ float feats[TILE * 8];
    const int t     = threadIdx.x;
    const int col4  = t % 12;
    const int rbase = t / 12;
    const size_t row0 = (size_t)blockIdx.x * TILE;

    vf4 Wv[8];
    #pragma unroll
    for (int w = 0; w < 8; ++w)
        Wv[w] = ((const vf4*)(W + w * OUT_DIM))[col4];

    const float* __restrict__ c1 = codes + LVL0 * 4;
    #pragma unroll
    for (int half = 0; half < 2; ++half) {
        const int r = half * 192 + t;
        if (half == 0 || t < TILE - 192) {
            const vi4 m0 = __builtin_nontemporal_load(&map0[row0 + r]);
            const vi4 m1 = __builtin_nontemporal_load(&map1[row0 + r]);
            vf4 a, b;
            a.x = codes[m0.x * 4 + 0];
            a.y = codes[m0.y * 4 + 1];
            a.z = codes[m0.z * 4 + 2];
            a.w = codes[m0.w * 4 + 3];
            b.x = c1[m1.x * 4 + 0];
            b.y = c1[m1.y * 4 + 1];
            b.z = c1[m1.z * 4 + 2];
            b.w = c1[m1.w * 4 + 3];
            *(vf4*)&feats[r * 8]     = a;
            *(vf4*)&feats[r * 8 + 4] = b;
        }
    }
    __syncthreads();

    vf4* __restrict__ out4 = (vf4*)(out + row0 * OUT_DIM);
    #pragma unroll
    for (int j = 0; j < NITER; ++j) {
        const int r = j * 16 + rbase;
        const vf4 fa = *(const vf4*)&feats[r * 8];
        const vf4 fb = *(const vf4*)&feats[r * 8 + 4];
        vf4 acc = fa.x * Wv[0];
        acc += fa.y * Wv[1];
        acc += fa.z * Wv[2];
        acc += fa.w * Wv[3];
        acc += fb.x * Wv[4];
        acc += fb.y * Wv[5];
        acc += fb.z * Wv[6];
        acc += fb.w * Wv[7];
        __builtin_nontemporal_store(acc, &out4[j * 192 + t]);
    }
}

extern "C" void kernel_launch(void* const* d_in, const int* in_sizes, int n_in,
                              void* d_out, int out_size, void* d_ws, size_t ws_size,
                              hipStream_t stream) {
    const float* codes = (const float*)d_in[0];
    const float* W     = (const float*)d_in[1];
    const vi4*   map0  = (const vi4*)d_in[2];
    const vi4*   map1  = (const vi4*)d_in[3];
    float*       out   = (float*)d_out;

    const size_t tab_bytes = (size_t)NCODES * 4 * sizeof(unsigned short); // 2.62 MB

    if (ws_size >= tab_bytes) {
        unsigned short* tab = (unsigned short*)d_ws;
        convert_kernel<<<NCODES / 256, 256, 0, stream>>>(codes, tab);
        gshash_pc_kernel<<<NBLK, BLK, 0, stream>>>(tab, W, map0, map1, out);
    } else {
        gshash_f32_kernel<<<RESO / TILE, 192, 0, stream>>>(codes, W, map0, map1, out);
    }
}

// Round 11
// 154.490 us; speedup vs baseline: 1.0467x; 1.0467x over previous
//
#include <hip/hip_runtime.h>

// GSHashEncoding R11: depth-2 gather pipeline (R9) + high occupancy (R7).
// R10 post-mortem: wave specialization starved gather issue (4 waves/CU).
// Model: gather ~3.3cy/lane-load/CU (~90us chip), loaded latency ~1270cy;
// need BOTH >=2 consume phases of slack (depth-2) AND many waves/CU so
// stalled waves are covered. R9 had depth-2 but 12 waves/CU; R7 had 24
// waves/CU but depth-1. This: TPB=4 -> NBLK=2048 (8 blocks/CU, 24 waves/CU,
// 128KB LDS/CU) with depth-2.
//   k1: codes fp32 -> bf16 table in ws (2.62 MB, L2-resident per XCD).

#define RESO    2097152
#define OUT_DIM 48
#define LVL0    65536
#define NCODES  327680
#define BLK     192                    // 3 waves; 192 % 12 == 0
#define TILE    256
#define NITER   16                     // TILE / (BLK/12)
#define TPB     4                      // tiles per block
#define NBLK    (RESO / (TILE * TPB))  // 2048 -> 8 blocks/CU

typedef int            vi4 __attribute__((ext_vector_type(4)));
typedef float          vf4 __attribute__((ext_vector_type(4)));
typedef unsigned short vu4 __attribute__((ext_vector_type(4)));

static __device__ __forceinline__ unsigned short f2bf_rne(float x) {
    unsigned int u = __float_as_uint(x);
    u += 0x7fffu + ((u >> 16) & 1u);
    return (unsigned short)(u >> 16);
}
static __device__ __forceinline__ float bf2f(unsigned short h) {
    return __uint_as_float(((unsigned int)h) << 16);
}

// Barrier that waits only on LDS ops (no vmcnt drain of stores/gathers).
static __device__ __forceinline__ void barrier_lds_only() {
    __builtin_amdgcn_sched_barrier(0);
    asm volatile("s_waitcnt lgkmcnt(0)" ::: "memory");
    __builtin_amdgcn_s_barrier();
    __builtin_amdgcn_sched_barrier(0);
}

// ---- k1: codes fp32 -> bf16 table ----
__global__ __launch_bounds__(256) void convert_kernel(
    const float* __restrict__ codes, unsigned short* __restrict__ bf)
{
    const int i = blockIdx.x * 256 + threadIdx.x;
    const vf4 v = ((const vf4*)codes)[i];
    vu4 o;
    o.x = f2bf_rne(v.x); o.y = f2bf_rne(v.y);
    o.z = f2bf_rne(v.z); o.w = f2bf_rne(v.w);
    ((vu4*)bf)[i] = o;
}

// ---- k2: depth-2 pipelined fused kernel, 8 blocks/CU ----
__global__ __launch_bounds__(BLK) void gshash_pipe_kernel(
    const unsigned short* __restrict__ tab,
    const float* __restrict__ W,
    const vi4*   __restrict__ map0,
    const vi4*   __restrict__ map1,
    float*       __restrict__ out)
{
    __shared__ float feats[2][TILE * 8];   // 16 KB double buffer

    const int t     = threadIdx.x;
    const int col4  = t % 12;
    const int rbase = t / 12;

    vf4 Wv[8];
    #pragma unroll
    for (int k = 0; k < 8; ++k)
        Wv[k] = ((const vf4*)(W + k * OUT_DIM))[col4];

    const unsigned short* __restrict__ t1 = tab + LVL0 * 4;
    const size_t row00 = (size_t)blockIdx.x * (TPB * TILE);

    vi4 m0b[3], m1b[3], n0b[3], n1b[3];    // triple-buffered map regs
    unsigned short gA[16], gB[16];         // depth-2 in-flight gather buffers

    #define LOADMAPS(j, s) {                                                  \
        const size_t r0 = row00 + (size_t)(j) * TILE;                         \
        m0b[s] = __builtin_nontemporal_load(&map0[r0 + t]);                   \
        m1b[s] = __builtin_nontemporal_load(&map1[r0 + t]);                   \
        if (t < TILE - BLK) {                                                 \
            n0b[s] = __builtin_nontemporal_load(&map0[r0 + BLK + t]);         \
            n1b[s] = __builtin_nontemporal_load(&map1[r0 + BLK + t]);         \
        } }

    #define GATHERS(s, G) {                                                   \
        G[0] = tab[m0b[s].x * 4 + 0];                                         \
        G[1] = tab[m0b[s].y * 4 + 1];                                         \
        G[2] = tab[m0b[s].z * 4 + 2];                                         \
        G[3] = tab[m0b[s].w * 4 + 3];                                         \
        G[4] = t1[m1b[s].x * 4 + 0];                                          \
        G[5] = t1[m1b[s].y * 4 + 1];                                          \
        G[6] = t1[m1b[s].z * 4 + 2];                                          \
        G[7] = t1[m1b[s].w * 4 + 3];                                          \
        if (t < TILE - BLK) {                                                 \
            G[8]  = tab[n0b[s].x * 4 + 0];                                    \
            G[9]  = tab[n0b[s].y * 4 + 1];                                    \
            G[10] = tab[n0b[s].z * 4 + 2];                                    \
            G[11] = tab[n0b[s].w * 4 + 3];                                    \
            G[12] = t1[n1b[s].x * 4 + 0];                                     \
            G[13] = t1[n1b[s].y * 4 + 1];                                     \
            G[14] = t1[n1b[s].z * 4 + 2];                                     \
            G[15] = t1[n1b[s].w * 4 + 3];                                     \
        } }

    #define LDSWRITE(G, buf) {                                                \
        vf4 a, b;                                                             \
        a.x = bf2f(G[0]); a.y = bf2f(G[1]); a.z = bf2f(G[2]); a.w = bf2f(G[3]); \
        b.x = bf2f(G[4]); b.y = bf2f(G[5]); b.z = bf2f(G[6]); b.w = bf2f(G[7]); \
        *(vf4*)&feats[buf][t * 8]     = a;                                    \
        *(vf4*)&feats[buf][t * 8 + 4] = b;                                    \
        if (t < TILE - BLK) {                                                 \
            vf4 c, d;                                                         \
            c.x = bf2f(G[8]);  c.y = bf2f(G[9]);  c.z = bf2f(G[10]); c.w = bf2f(G[11]); \
            d.x = bf2f(G[12]); d.y = bf2f(G[13]); d.z = bf2f(G[14]); d.w = bf2f(G[15]); \
            *(vf4*)&feats[buf][(BLK + t) * 8]     = c;                        \
            *(vf4*)&feats[buf][(BLK + t) * 8 + 4] = d;                        \
        } }

    // prolog: maps for tiles 0,1,2; gather tile0 -> LDS[0]; issue tile1 gathers
    LOADMAPS(0, 0);
    LOADMAPS(1, 1);
    LOADMAPS(2, 2);
    GATHERS(0, gA);                    // tile 0 (even -> gA)
    LDSWRITE(gA, 0);                   // exposed once per block (covered by other blocks)
    GATHERS(1, gB);                    // tile 1 (odd -> gB)
    barrier_lds_only();

    #pragma unroll
    for (int i = 0; i < TPB; ++i) {
        const int cur = i & 1;

        if (i + 3 < TPB) LOADMAPS(i + 3, (i + 3) % 3);
        if (i + 2 < TPB) {                       // issue gathers 2 tiles ahead
            if (((i + 2) & 1) == 0) { GATHERS((i + 2) % 3, gA); }
            else                    { GATHERS((i + 2) % 3, gB); }
        }

        // consume tile i
        vf4* __restrict__ out4 = (vf4*)(out + (row00 + (size_t)i * TILE) * OUT_DIM);
        #pragma unroll
        for (int j = 0; j < NITER; ++j) {
            const int r = j * 16 + rbase;
            const vf4 fa = *(const vf4*)&feats[cur][r * 8];
            const vf4 fb = *(const vf4*)&feats[cur][r * 8 + 4];
            vf4 acc = fa.x * Wv[0];
            acc += fa.y * Wv[1];
            acc += fa.z * Wv[2];
            acc += fa.w * Wv[3];
            acc += fb.x * Wv[4];
            acc += fb.y * Wv[5];
            acc += fb.z * Wv[6];
            acc += fb.w * Wv[7];
            __builtin_nontemporal_store(acc, &out4[j * BLK + t]);
        }

        if (i + 1 < TPB) {                       // 2 consume phases of slack
            if (((i + 1) & 1) == 0) { LDSWRITE(gA, 0); }
            else                    { LDSWRITE(gB, 1); }
            barrier_lds_only();
        }
    }
    #undef LOADMAPS
    #undef GATHERS
    #undef LDSWRITE
}

// ---- fallback: fused fp32 single-tile kernel (if ws too small) ----
__global__ __launch_bounds__(BLK) void gshash_f32_kernel(
    const float* __restrict__ codes,
    const float* __restrict__ W,
    const vi4*   __restrict__ map0,
    const vi4*   __restrict__ map1,
    float*       __restrict__ out)
{
    __shared__ float feats[TILE * 8];
    const int t     = threadIdx.x;
    const int col4  = t % 12;
    const int rbase = t / 12;
    const size_t row0 = (size_t)blockIdx.x * TILE;

    vf4 Wv[8];
    #pragma unroll
    for (int w = 0; w < 8; ++w)
        Wv[w] = ((const vf4*)(W + w * OUT_DIM))[col4];

    const float* __restrict__ c1 = codes + LVL0 * 4;
    #pragma unroll
    for (int half = 0; half < 2; ++half) {
        const int r = half * BLK + t;
        if (half == 0 || t < TILE - BLK) {
            const vi4 m0 = __builtin_nontemporal_load(&map0[row0 + r]);
            const vi4 m1 = __builtin_nontemporal_load(&map1[row0 + r]);
            vf4 a, b;
            a.x = codes[m0.x * 4 + 0];
            a.y = codes[m0.y * 4 + 1];
            a.z = codes[m0.z * 4 + 2];
            a.w = codes[m0.w * 4 + 3];
            b.x = c1[m1.x * 4 + 0];
            b.y = c1[m1.y * 4 + 1];
            b.z = c1[m1.z * 4 + 2];
            b.w = c1[m1.w * 4 + 3];
            *(vf4*)&feats[r * 8]     = a;
            *(vf4*)&feats[r * 8 + 4] = b;
        }
    }
    __syncthreads();

    vf4* __restrict__ out4 = (vf4*)(out + row0 * OUT_DIM);
    #pragma unroll
    for (int j = 0; j < NITER; ++j) {
        const int r = j * 16 + rbase;
        const vf4 fa = *(const vf4*)&feats[r * 8];
        const vf4 fb = *(const vf4*)&feats[r * 8 + 4];
        vf4 acc = fa.x * Wv[0];
        acc += fa.y * Wv[1];
        acc += fa.z * Wv[2];
        acc += fa.w * Wv[3];
        acc += fb.x * Wv[4];
        acc += fb.y * Wv[5];
        acc += fb.z * Wv[6];
        acc += fb.w * Wv[7];
        __builtin_nontemporal_store(acc, &out4[j * BLK + t]);
    }
}

extern "C" void kernel_launch(void* const* d_in, const int* in_sizes, int n_in,
                              void* d_out, int out_size, void* d_ws, size_t ws_size,
                              hipStream_t stream) {
    const float* codes = (const float*)d_in[0];
    const float* W     = (const float*)d_in[1];
    const vi4*   map0  = (const vi4*)d_in[2];
    const vi4*   map1  = (const vi4*)d_in[3];
    float*       out   = (float*)d_out;

    const size_t tab_bytes = (size_t)NCODES * 4 * sizeof(unsigned short); // 2.62 MB

    if (ws_size >= tab_bytes) {
        unsigned short* tab = (unsigned short*)d_ws;
        convert_kernel<<<NCODES / 256, 256, 0, stream>>>(codes, tab);
        gshash_pipe_kernel<<<NBLK, BLK, 0, stream>>>(tab, W, map0, map1, out);
    } else {
        gshash_f32_kernel<<<RESO / TILE, BLK, 0, stream>>>(codes, W, map0, map1, out);
    }
}

// Round 13
// 141.824 us; speedup vs baseline: 1.1402x; 1.0893x over previous
//
#include <hip/hip_runtime.h>

// GSHashEncoding R13 = R9 (best: 140.8us), restored after R12 crash.
// Model (validated on R4/R5/R9/R10/R11): per-CU vector-memory line-request
// service ~3.6cy/64B-line is the binding resource. Total lines: gathers
// 16.7M + stores 6.3M + maps 1M = 24M -> floor ~139us. R9 = 140.8 (+1.3%).
// Scheduling cannot beat a shared-throughput port; this config saturates it.
//   k1: codes fp32 -> bf16 table in ws (2.62 MB, L2-resident).
//   k2: TPB=8 (NBLK=1024, 4 blocks/CU), depth-2 gather pipeline (2 reg
//       g-buffers, maps triple-buffered), LDS double-buffer, lgkm-only
//       barriers (no vmcnt drain of stores/gathers).

#define RESO    2097152
#define OUT_DIM 48
#define LVL0    65536
#define NCODES  327680
#define BLK     192                    // 3 waves; 192 % 12 == 0
#define TILE    256
#define NITER   16                     // TILE / (BLK/12)
#define TPB     8                      // tiles per block
#define NBLK    (RESO / (TILE * TPB))  // 1024

typedef int            vi4 __attribute__((ext_vector_type(4)));
typedef float          vf4 __attribute__((ext_vector_type(4)));
typedef unsigned short vu4 __attribute__((ext_vector_type(4)));

static __device__ __forceinline__ unsigned short f2bf_rne(float x) {
    unsigned int u = __float_as_uint(x);
    u += 0x7fffu + ((u >> 16) & 1u);
    return (unsigned short)(u >> 16);
}
static __device__ __forceinline__ float bf2f(unsigned short h) {
    return __uint_as_float(((unsigned int)h) << 16);
}

// Barrier that waits only on LDS ops (no vmcnt drain of stores/gathers).
static __device__ __forceinline__ void barrier_lds_only() {
    __builtin_amdgcn_sched_barrier(0);
    asm volatile("s_waitcnt lgkmcnt(0)" ::: "memory");
    __builtin_amdgcn_s_barrier();
    __builtin_amdgcn_sched_barrier(0);
}

// ---- k1: codes fp32 -> bf16 table ----
__global__ __launch_bounds__(256) void convert_kernel(
    const float* __restrict__ codes, unsigned short* __restrict__ bf)
{
    const int i = blockIdx.x * 256 + threadIdx.x;
    const vf4 v = ((const vf4*)codes)[i];
    vu4 o;
    o.x = f2bf_rne(v.x); o.y = f2bf_rne(v.y);
    o.z = f2bf_rne(v.z); o.w = f2bf_rne(v.w);
    ((vu4*)bf)[i] = o;
}

// ---- k2: depth-2 pipelined fused kernel ----
__global__ __launch_bounds__(BLK) void gshash_pipe_kernel(
    const unsigned short* __restrict__ tab,
    const float* __restrict__ W,
    const vi4*   __restrict__ map0,
    const vi4*   __restrict__ map1,
    float*       __restrict__ out)
{
    __shared__ float feats[2][TILE * 8];   // 16 KB double buffer

    const int t     = threadIdx.x;
    const int col4  = t % 12;
    const int rbase = t / 12;

    vf4 Wv[8];
    #pragma unroll
    for (int k = 0; k < 8; ++k)
        Wv[k] = ((const vf4*)(W + k * OUT_DIM))[col4];

    const unsigned short* __restrict__ t1 = tab + LVL0 * 4;
    const size_t row00 = (size_t)blockIdx.x * (TPB * TILE);

    vi4 m0b[3], m1b[3], n0b[3], n1b[3];    // triple-buffered map regs
    unsigned short gA[16], gB[16];         // depth-2 in-flight gather buffers

    #define LOADMAPS(j, s) {                                                  \
        const size_t r0 = row00 + (size_t)(j) * TILE;                         \
        m0b[s] = __builtin_nontemporal_load(&map0[r0 + t]);                   \
        m1b[s] = __builtin_nontemporal_load(&map1[r0 + t]);                   \
        if (t < TILE - BLK) {                                                 \
            n0b[s] = __builtin_nontemporal_load(&map0[r0 + BLK + t]);         \
            n1b[s] = __builtin_nontemporal_load(&map1[r0 + BLK + t]);         \
        } }

    #define GATHERS(s, G) {                                                   \
        G[0] = tab[m0b[s].x * 4 + 0];                                         \
        G[1] = tab[m0b[s].y * 4 + 1];                                         \
        G[2] = tab[m0b[s].z * 4 + 2];                                         \
        G[3] = tab[m0b[s].w * 4 + 3];                                         \
        G[4] = t1[m1b[s].x * 4 + 0];                                          \
        G[5] = t1[m1b[s].y * 4 + 1];                                          \
        G[6] = t1[m1b[s].z * 4 + 2];                                          \
        G[7] = t1[m1b[s].w * 4 + 3];                                          \
        if (t < TILE - BLK) {                                                 \
            G[8]  = tab[n0b[s].x * 4 + 0];                                    \
            G[9]  = tab[n0b[s].y * 4 + 1];                                    \
            G[10] = tab[n0b[s].z * 4 + 2];                                    \
            G[11] = tab[n0b[s].w * 4 + 3];                                    \
            G[12] = t1[n1b[s].x * 4 + 0];                                     \
            G[13] = t1[n1b[s].y * 4 + 1];                                     \
            G[14] = t1[n1b[s].z * 4 + 2];                                     \
            G[15] = t1[n1b[s].w * 4 + 3];                                     \
        } }

    #define LDSWRITE(G, buf) {                                                \
        vf4 a, b;                                                             \
        a.x = bf2f(G[0]); a.y = bf2f(G[1]); a.z = bf2f(G[2]); a.w = bf2f(G[3]); \
        b.x = bf2f(G[4]); b.y = bf2f(G[5]); b.z = bf2f(G[6]); b.w = bf2f(G[7]); \
        *(vf4*)&feats[buf][t * 8]     = a;                                    \
        *(vf4*)&feats[buf][t * 8 + 4] = b;                                    \
        if (t < TILE - BLK) {                                                 \
            vf4 c, d;                                                         \
            c.x = bf2f(G[8]);  c.y = bf2f(G[9]);  c.z = bf2f(G[10]); c.w = bf2f(G[11]); \
            d.x = bf2f(G[12]); d.y = bf2f(G[13]); d.z = bf2f(G[14]); d.w = bf2f(G[15]); \
            *(vf4*)&feats[buf][(BLK + t) * 8]     = c;                        \
            *(vf4*)&feats[buf][(BLK + t) * 8 + 4] = d;                        \
        } }

    // prolog: maps for tiles 0,1,2; gather tile0 -> LDS[0]; issue tile1 gathers
    LOADMAPS(0, 0);
    LOADMAPS(1, 1);
    LOADMAPS(2, 2);
    GATHERS(0, gA);                    // tile 0 (even -> gA)
    LDSWRITE(gA, 0);                   // exposed once per block
    GATHERS(1, gB);                    // tile 1 (odd -> gB); waited next iter
    barrier_lds_only();

    #pragma unroll
    for (int i = 0; i < TPB; ++i) {
        const int cur = i & 1;

        if (i + 3 < TPB) LOADMAPS(i + 3, (i + 3) % 3);
        if (i + 2 < TPB) {                       // issue gathers 2 tiles ahead
            if (((i + 2) & 1) == 0) { GATHERS((i + 2) % 3, gA); }
            else                    { GATHERS((i + 2) % 3, gB); }
        }

        // consume tile i
        vf4* __restrict__ out4 = (vf4*)(out + (row00 + (size_t)i * TILE) * OUT_DIM);
        #pragma unroll
        for (int j = 0; j < NITER; ++j) {
            const int r = j * 16 + rbase;
            const vf4 fa = *(const vf4*)&feats[cur][r * 8];
            const vf4 fb = *(const vf4*)&feats[cur][r * 8 + 4];
            vf4 acc = fa.x * Wv[0];
            acc += fa.y * Wv[1];
            acc += fa.z * Wv[2];
            acc += fa.w * Wv[3];
            acc += fb.x * Wv[4];
            acc += fb.y * Wv[5];
            acc += fb.z * Wv[6];
            acc += fb.w * Wv[7];
            __builtin_nontemporal_store(acc, &out4[j * BLK + t]);
        }

        if (i + 1 < TPB) {                       // gathers had 2 consume phases of slack
            if (((i + 1) & 1) == 0) { LDSWRITE(gA, 0); }
            else                    { LDSWRITE(gB, 1); }
            barrier_lds_only();
        }
    }
    #undef LOADMAPS
    #undef GATHERS
    #undef LDSWRITE
}

// ---- fallback: fused fp32 single-tile kernel (if ws too small) ----
__global__ __launch_bounds__(BLK) void gshash_f32_kernel(
    const float* __restrict__ codes,
    const float* __restrict__ W,
    const vi4*   __restrict__ map0,
    const vi4*   __restrict__ map1,
    float*       __restrict__ out)
{
    __shared__ float feats[TILE * 8];
    const int t     = threadIdx.x;
    const int col4  = t % 12;
    const int rbase = t / 12;
    const size_t row0 = (size_t)blockIdx.x * TILE;

    vf4 Wv[8];
    #pragma unroll
    for (int w = 0; w < 8; ++w)
        Wv[w] = ((const vf4*)(W + w * OUT_DIM))[col4];

    const float* __restrict__ c1 = codes + LVL0 * 4;
    #pragma unroll
    for (int half = 0; half < 2; ++half) {
        const int r = half * BLK + t;
        if (half == 0 || t < TILE - BLK) {
            const vi4 m0 = __builtin_nontemporal_load(&map0[row0 + r]);
            const vi4 m1 = __builtin_nontemporal_load(&map1[row0 + r]);
            vf4 a, b;
            a.x = codes[m0.x * 4 + 0];
            a.y = codes[m0.y * 4 + 1];
            a.z = codes[m0.z * 4 + 2];
            a.w = codes[m0.w * 4 + 3];
            b.x = c1[m1.x * 4 + 0];
            b.y = c1[m1.y * 4 + 1];
            b.z = c1[m1.z * 4 + 2];
            b.w = c1[m1.w * 4 + 3];
            *(vf4*)&feats[r * 8]     = a;
            *(vf4*)&feats[r * 8 + 4] = b;
        }
    }
    __syncthreads();

    vf4* __restrict__ out4 = (vf4*)(out + row0 * OUT_DIM);
    #pragma unroll
    for (int j = 0; j < NITER; ++j) {
        const int r = j * 16 + rbase;
        const vf4 fa = *(const vf4*)&feats[r * 8];
        const vf4 fb = *(const vf4*)&feats[r * 8 + 4];
        vf4 acc = fa.x * Wv[0];
        acc += fa.y * Wv[1];
        acc += fa.z * Wv[2];
        acc += fa.w * Wv[3];
        acc += fb.x * Wv[4];
        acc += fb.y * Wv[5];
        acc += fb.z * Wv[6];
        acc += fb.w * Wv[7];
        __builtin_nontemporal_store(acc, &out4[j * BLK + t]);
    }
}

extern "C" void kernel_launch(void* const* d_in, const int* in_sizes, int n_in,
                              void* d_out, int out_size, void* d_ws, size_t ws_size,
                              hipStream_t stream) {
    const float* codes = (const float*)d_in[0];
    const float* W     = (const float*)d_in[1];
    const vi4*   map0  = (const vi4*)d_in[2];
    const vi4*   map1  = (const vi4*)d_in[3];
    float*       out   = (float*)d_out;

    const size_t tab_bytes = (size_t)NCODES * 4 * sizeof(unsigned short); // 2.62 MB

    if (ws_size >= tab_bytes) {
        unsigned short* tab = (unsigned short*)d_ws;
        convert_kernel<<<NCODES / 256, 256, 0, stream>>>(codes, tab);
        gshash_pipe_kernel<<<NBLK, BLK, 0, stream>>>(tab, W, map0, map1, out);
    } else {
        gshash_f32_kernel<<<RESO / TILE, BLK, 0, stream>>>(codes, W, map0, map1, out);
    }
}